// Round 5
// baseline (471.209 us; speedup 1.0000x reference)
//
#include <hip/hip_runtime.h>

#define NTOK 49
#define NHEAD 8
#define HDIM 32
#define DIMC 256
#define SCALE_F 0.17677669529663687f

typedef __attribute__((ext_vector_type(8))) short short8;
typedef __attribute__((ext_vector_type(4))) float f32x4;

#define AS1P(p) ((__attribute__((address_space(1))) void*)(p))
#define AS3P(p) ((__attribute__((address_space(3))) void*)(p))

__device__ inline unsigned short f2bf(float f) {
    unsigned int u = __float_as_uint(f);
    u += 0x7fffu + ((u >> 16) & 1u);
    return (unsigned short)(u >> 16);
}

// ---------------- pack W[K,N] fp32 -> Wp[K/8][N][8] bf16 --------------------
__global__ __launch_bounds__(256) void pack_w(const float* __restrict__ W,
    unsigned short* __restrict__ Wp, int K, int N)
{
    int idx = blockIdx.x * 256 + threadIdx.x;
    if (idx >= K * N) return;
    int k = idx / N, n = idx - k * N;
    Wp[((size_t)(k >> 3) * N + n) * 8 + (k & 7)] = f2bf(W[idx]);
}

// ---------------- bias+mask combined table bm[w][h][i][j] -------------------
__global__ __launch_bounds__(256) void bm_build(const float* __restrict__ bias_table,
    const int* __restrict__ rel_index, const float* __restrict__ mask,
    float* __restrict__ bm)
{
    int idx = blockIdx.x * 256 + threadIdx.x;
    if (idx >= 64 * NHEAD * NTOK * NTOK) return;
    int wh = idx / (NTOK * NTOK);
    int ij = idx - wh * (NTOK * NTOK);
    int w = wh >> 3, h = wh & 7;
    bm[idx] = bias_table[rel_index[ij] * NHEAD + h] + mask[(size_t)w * (NTOK * NTOK) + ij];
}

// ---------------- bf16 MFMA GEMM: Y[M,N] = A[M,256] @ W[256,N] + Bv ---------
// 128x128 tile, 4 waves, BK=32, K=256 (8 steps, fully unrolled).
// A_F32 path (QKV): A fragments loaded DIRECTLY from row-major fp32 x
//   (k-contiguous per lane), converted in-register; reg-prefetch 1 step ahead.
//   Only B goes through LDS (double-buffered) -> ONE barrier per k-step.
// packed path (proj): A,B both k-major packed bf16 via global_load_lds into
//   double-buffered LDS, glds issued one step ahead, one barrier per step.
// Swapped-operand MFMA (C^T fragments) -> vectorized epilogue.
template <bool A_F32, bool OUT_BF16>
__global__ __launch_bounds__(256) void gemm_mfma(
    const void* __restrict__ Av,
    const unsigned short* __restrict__ Wp,   // [32][N][8] bf16 packed
    const float* __restrict__ Bv,            // [N]
    void* __restrict__ Yv,                   // [M][N]
    int N, int M, int nbm)
{
    // Bs buffers at SM + buf*4096 ; As buffers (packed path) at SM + 8192 + buf*4096
    __shared__ __align__(16) unsigned short SM[A_F32 ? 8192 : 16384];

    const int tid  = threadIdx.x;
    const int lane = tid & 63;
    const int wv   = tid >> 6;
    const int quad = lane >> 4;
    const int l15  = lane & 15;

    // XCD-aware block swizzle: each XCD gets a contiguous m-range, with the
    // nbn column-blocks of one m-tile consecutive in that XCD's sequence.
    const int nbn = N >> 7;
    const int lin = blockIdx.x;
    int mblk, nblk;
    if ((nbm & 7) == 0) {
        const int xcd = lin & 7;
        const int g   = lin >> 3;
        const int gm  = g / nbn;
        mblk = xcd * (nbm >> 3) + gm;
        nblk = g - gm * nbn;
    } else {
        mblk = lin / nbn;
        nblk = lin - mblk * nbn;
    }
    const long m0 = (long)mblk * 128;
    const int  n0 = nblk * 128;
    const int  wm = (wv >> 1) * 64;
    const int  wn = (wv & 1) * 64;

    // B staging pointers (wave wv stages k-chunk 4*ks + wv; 64 lanes x 16B)
    const unsigned short* gb0 = Wp + ((size_t)wv * N + n0 + lane) * 8;
    const unsigned short* gb1 = gb0 + 64 * 8;

    f32x4 acc[4][4];
    #pragma unroll
    for (int i = 0; i < 4; ++i)
        #pragma unroll
        for (int j = 0; j < 4; ++j) acc[i][j] = (f32x4){0.f, 0.f, 0.f, 0.f};

    if constexpr (!A_F32) {
        // ---------------- packed-A path (proj GEMM) ----------------
        const unsigned short* ga0 = (const unsigned short*)Av + ((size_t)wv * M + m0 + lane) * 8;
        const unsigned short* ga1 = ga0 + 64 * 8;
        // prologue: stage step 0 into buffer 0
        __builtin_amdgcn_global_load_lds(AS1P(ga0), AS3P(SM + 8192 + wv * 1024),       16, 0, 0);
        __builtin_amdgcn_global_load_lds(AS1P(ga1), AS3P(SM + 8192 + wv * 1024 + 512), 16, 0, 0);
        __builtin_amdgcn_global_load_lds(AS1P(gb0), AS3P(SM + wv * 1024),              16, 0, 0);
        __builtin_amdgcn_global_load_lds(AS1P(gb1), AS3P(SM + wv * 1024 + 512),        16, 0, 0);
        __syncthreads();
        #pragma unroll
        for (int ks = 0; ks < 8; ++ks) {
            const int cur = ks & 1;
            if (ks < 7) {
                const int alt = (ks + 1) & 1;
                const size_t aofs = (size_t)(ks + 1) * 4 * M * 8;
                const size_t bofs = (size_t)(ks + 1) * 4 * N * 8;
                __builtin_amdgcn_global_load_lds(AS1P(ga0 + aofs), AS3P(SM + 8192 + alt * 4096 + wv * 1024),       16, 0, 0);
                __builtin_amdgcn_global_load_lds(AS1P(ga1 + aofs), AS3P(SM + 8192 + alt * 4096 + wv * 1024 + 512), 16, 0, 0);
                __builtin_amdgcn_global_load_lds(AS1P(gb0 + bofs), AS3P(SM + alt * 4096 + wv * 1024),              16, 0, 0);
                __builtin_amdgcn_global_load_lds(AS1P(gb1 + bofs), AS3P(SM + alt * 4096 + wv * 1024 + 512),        16, 0, 0);
            }
            short8 af[4], bq[4];
            #pragma unroll
            for (int t = 0; t < 4; ++t) {
                af[t] = *(const short8*)(SM + 8192 + cur * 4096 + quad * 1024 + (wm + t * 16 + l15) * 8);
                bq[t] = *(const short8*)(SM + cur * 4096 + quad * 1024 + (wn + t * 16 + l15) * 8);
            }
            #pragma unroll
            for (int ti = 0; ti < 4; ++ti)
                #pragma unroll
                for (int tj = 0; tj < 4; ++tj)
                    acc[ti][tj] = __builtin_amdgcn_mfma_f32_16x16x32_bf16(bq[tj], af[ti], acc[ti][tj], 0, 0, 0);
            __syncthreads();
        }
    } else {
        // ---------------- fused-cvt path (QKV GEMM) ----------------
        // A fragment is k-contiguous in row-major x: load direct, cvt in-reg.
        const float* X = (const float*)Av;
        const float* ar[4];
        #pragma unroll
        for (int t = 0; t < 4; ++t)
            ar[t] = X + (size_t)(m0 + wm + t * 16 + l15) * 256 + quad * 8;

        float4 pf0[4][2], pf1[4][2];
        __builtin_amdgcn_global_load_lds(AS1P(gb0), AS3P(SM + wv * 1024),       16, 0, 0);
        __builtin_amdgcn_global_load_lds(AS1P(gb1), AS3P(SM + wv * 1024 + 512), 16, 0, 0);
        #pragma unroll
        for (int t = 0; t < 4; ++t) {
            pf0[t][0] = ((const float4*)ar[t])[0];
            pf0[t][1] = ((const float4*)ar[t])[1];
        }
        __syncthreads();

        #define QKV_STEP(ks, PC, PN)                                                  \
        {                                                                             \
            short8 af[4], bq[4];                                                      \
            _Pragma("unroll")                                                         \
            for (int t = 0; t < 4; ++t) {                                             \
                union { unsigned short s[8]; short8 v; } u;                           \
                u.s[0] = f2bf(PC[t][0].x); u.s[1] = f2bf(PC[t][0].y);                 \
                u.s[2] = f2bf(PC[t][0].z); u.s[3] = f2bf(PC[t][0].w);                 \
                u.s[4] = f2bf(PC[t][1].x); u.s[5] = f2bf(PC[t][1].y);                 \
                u.s[6] = f2bf(PC[t][1].z); u.s[7] = f2bf(PC[t][1].w);                 \
                af[t] = u.v;                                                          \
            }                                                                         \
            if (ks < 7) {                                                             \
                const int alt = (ks + 1) & 1;                                         \
                const size_t bofs = (size_t)(ks + 1) * 4 * N * 8;                     \
                __builtin_amdgcn_global_load_lds(AS1P(gb0 + bofs), AS3P(SM + alt * 4096 + wv * 1024),       16, 0, 0); \
                __builtin_amdgcn_global_load_lds(AS1P(gb1 + bofs), AS3P(SM + alt * 4096 + wv * 1024 + 512), 16, 0, 0); \
                _Pragma("unroll")                                                     \
                for (int t = 0; t < 4; ++t) {                                         \
                    PN[t][0] = ((const float4*)(ar[t] + (ks + 1) * 32))[0];           \
                    PN[t][1] = ((const float4*)(ar[t] + (ks + 1) * 32))[1];           \
                }                                                                     \
            }                                                                         \
            _Pragma("unroll")                                                         \
            for (int t = 0; t < 4; ++t)                                               \
                bq[t] = *(const short8*)(SM + (ks & 1) * 4096 + quad * 1024 + (wn + t * 16 + l15) * 8); \
            _Pragma("unroll")                                                         \
            for (int ti = 0; ti < 4; ++ti)                                            \
                _Pragma("unroll")                                                     \
                for (int tj = 0; tj < 4; ++tj)                                        \
                    acc[ti][tj] = __builtin_amdgcn_mfma_f32_16x16x32_bf16(bq[tj], af[ti], acc[ti][tj], 0, 0, 0); \
            __syncthreads();                                                          \
        }
        QKV_STEP(0, pf0, pf1) QKV_STEP(1, pf1, pf0) QKV_STEP(2, pf0, pf1) QKV_STEP(3, pf1, pf0)
        QKV_STEP(4, pf0, pf1) QKV_STEP(5, pf1, pf0) QKV_STEP(6, pf0, pf1) QKV_STEP(7, pf1, pf0)
        #undef QKV_STEP
    }

    // vectorized epilogue: per (ti,tj) one 8B (bf16) or 16B (fp32) store
    float4 bv4[4];
    #pragma unroll
    for (int tj = 0; tj < 4; ++tj)
        bv4[tj] = *(const float4*)(Bv + n0 + wn + tj * 16 + quad * 4);

    #pragma unroll
    for (int ti = 0; ti < 4; ++ti) {
        const long row = m0 + wm + ti * 16 + l15;
        #pragma unroll
        for (int tj = 0; tj < 4; ++tj) {
            const int col = n0 + wn + tj * 16 + quad * 4;
            const float v0 = acc[ti][tj][0] + bv4[tj].x;
            const float v1 = acc[ti][tj][1] + bv4[tj].y;
            const float v2 = acc[ti][tj][2] + bv4[tj].z;
            const float v3 = acc[ti][tj][3] + bv4[tj].w;
            if (OUT_BF16) {
                uint2 u;
                u.x = (unsigned int)f2bf(v0) | ((unsigned int)f2bf(v1) << 16);
                u.y = (unsigned int)f2bf(v2) | ((unsigned int)f2bf(v3) << 16);
                *(uint2*)((unsigned short*)Yv + row * N + col) = u;
            } else {
                float4 o = {v0, v1, v2, v3};
                *(float4*)((float*)Yv + row * N + col) = o;
            }
        }
    }
}

// ---------------- MFMA attention: 2 waves/block, direct Q/K frag loads ------
// qkvb: [wc*49][768] bf16, col = s*256 + h*32 + d.
// o1b: k-major packed [32][Mc][8] bf16 (feeds proj GEMM's A path), written
// via LDS slab restage -> 49x16B contiguous stores per k-group.
// Softmax WITHOUT max-subtraction: scores for this problem are bounded
// (|s| < ~1), so exp is safe; expf(-inf)=0 handles col>=49 padding.
__global__ __launch_bounds__(128) void attn_mfma(
    const unsigned short* __restrict__ qkvb,
    const float* __restrict__ bm,        // [64][8][49][49]
    unsigned short* __restrict__ o1b,
    int win0, int Mc)
{
    __shared__ __align__(16) unsigned short SMEM[2 * 3528];

    const int wvid = threadIdx.x >> 6;
    const int lane = threadIdx.x & 63;
    const int h    = blockIdx.x * 2 + wvid;     // head
    const int b    = blockIdx.y;                // local window
    const int w    = (win0 + b) & 63;
    const int quad = lane >> 4;
    const int l15  = lane & 15;

    unsigned short* Vt = SMEM + wvid * 3528;   // [32 d][72], phase 1
    unsigned short* Ps = SMEM + wvid * 3528;   // [49 row][72], phase 2
    unsigned short* Os = SMEM + wvid * 3528;   // [4 kg][49][8], phase 3

    const unsigned short* wbase = qkvb + (size_t)b * NTOK * 768 + h * HDIM;

    // ---- stage V^T: lane = token (clamped), 32 scalar b16 writes ----
    {
        const int tok = (lane < NTOK) ? lane : (NTOK - 1);
        const unsigned short* vp = wbase + (size_t)tok * 768 + 512;
        #pragma unroll
        for (int c = 0; c < 4; ++c) {
            uint4 vv = *(const uint4*)(vp + c * 8);
            unsigned int uu[4] = {vv.x, vv.y, vv.z, vv.w};
            #pragma unroll
            for (int e = 0; e < 4; ++e) {
                int d = c * 8 + e * 2;
                Vt[d * 72 + lane]       = (unsigned short)(uu[e] & 0xffffu);
                Vt[(d + 1) * 72 + lane] = (unsigned short)(uu[e] >> 16);
            }
        }
    }

    // ---- Q/K fragments direct from global (16B contiguous per lane) ----
    short8 aq[4], bk[4];
    #pragma unroll
    for (int t = 0; t < 4; ++t) {
        int row = t * 16 + l15; if (row >= NTOK) row = NTOK - 1;
        const unsigned short* rp = wbase + (size_t)row * 768 + quad * 8;
        aq[t] = *(const short8*)(rp);
        bk[t] = *(const short8*)(rp + 256);
    }

    // ---- S = Q K^T (16 mfma, K=32) ----
    f32x4 sa[4][4];
    #pragma unroll
    for (int ti = 0; ti < 4; ++ti)
        #pragma unroll
        for (int tj = 0; tj < 4; ++tj) {
            f32x4 z = (f32x4){0.f, 0.f, 0.f, 0.f};
            sa[ti][tj] = __builtin_amdgcn_mfma_f32_16x16x32_bf16(aq[ti], bk[tj], z, 0, 0, 0);
        }

    // ---- read V fragments BEFORE P overwrites the aliased LDS ----
    short8 vb2[2][2];
    #pragma unroll
    for (int td = 0; td < 2; ++td)
        #pragma unroll
        for (int kc = 0; kc < 2; ++kc)
            vb2[td][kc] = *(const short8*)(Vt + (td * 16 + l15) * 72 + kc * 32 + quad * 8);

    // ---- scale + bias + mask, softmax (no max-sub) across row ----
    const float* bmb = bm + (size_t)(w * NHEAD + h) * (NTOK * NTOK);
    float inv[4][4];
    #pragma unroll
    for (int ti = 0; ti < 4; ++ti) {
        #pragma unroll
        for (int r = 0; r < 4; ++r) {
            const int row = ti * 16 + quad * 4 + r;
            float sv[4];
            #pragma unroll
            for (int tj = 0; tj < 4; ++tj) {
                const int col = tj * 16 + l15;
                float s;
                if (col < NTOK) {
                    float add = (row < NTOK) ? bmb[row * NTOK + col] : 0.f;
                    s = sa[ti][tj][r] * SCALE_F + add;
                } else {
                    s = -__builtin_inff();
                }
                sv[tj] = s;
            }
            float e0 = __expf(sv[0]), e1 = __expf(sv[1]);
            float e2 = __expf(sv[2]), e3 = __expf(sv[3]);
            sa[ti][0][r] = e0; sa[ti][1][r] = e1; sa[ti][2][r] = e2; sa[ti][3][r] = e3;
            float sum = (e0 + e1) + (e2 + e3);
            sum += __shfl_xor(sum, 1, 16);
            sum += __shfl_xor(sum, 2, 16);
            sum += __shfl_xor(sum, 4, 16);
            sum += __shfl_xor(sum, 8, 16);
            inv[ti][r] = 1.f / sum;
        }
    }

    // ---- make sure both waves' V-fragment reads retired before P overwrite ----
    __syncthreads();

    // ---- P (unnormalized e, bf16) -> LDS row-major [49][72] ----
    #pragma unroll
    for (int ti = 0; ti < 4; ++ti)
        #pragma unroll
        for (int r = 0; r < 4; ++r) {
            const int row = ti * 16 + quad * 4 + r;
            if (row < NTOK) {
                #pragma unroll
                for (int tj = 0; tj < 4; ++tj)
                    Ps[row * 72 + tj * 16 + l15] = f2bf(sa[ti][tj][r]);
            }
        }

    // ---- O = P V (K=64 via 2 chunks), rows clamped (rows>=49 unused) ----
    short8 pa[4][2];
    #pragma unroll
    for (int ti = 0; ti < 4; ++ti) {
        int row = ti * 16 + l15; if (row >= NTOK) row = NTOK - 1;
        #pragma unroll
        for (int kc = 0; kc < 2; ++kc)
            pa[ti][kc] = *(const short8*)(Ps + row * 72 + kc * 32 + quad * 8);
    }
    f32x4 oa[4][2];
    #pragma unroll
    for (int ti = 0; ti < 4; ++ti)
        #pragma unroll
        for (int td = 0; td < 2; ++td) {
            f32x4 z = (f32x4){0.f, 0.f, 0.f, 0.f};
            z = __builtin_amdgcn_mfma_f32_16x16x32_bf16(pa[ti][0], vb2[td][0], z, 0, 0, 0);
            oa[ti][td] = __builtin_amdgcn_mfma_f32_16x16x32_bf16(pa[ti][1], vb2[td][1], z, 0, 0, 0);
        }

    // ---- normalize + restage O into wave-private slab LDS [4 kg][49][8] ----
    #pragma unroll
    for (int ti = 0; ti < 4; ++ti)
        #pragma unroll
        for (int r = 0; r < 4; ++r) {
            const int row = ti * 16 + quad * 4 + r;
            if (row < NTOK) {
                const float si = inv[ti][r];
                #pragma unroll
                for (int td = 0; td < 2; ++td) {
                    const int d = td * 16 + l15;    // 0..31 within head
                    Os[(d >> 3) * (NTOK * 8) + row * 8 + (d & 7)] =
                        f2bf(oa[ti][td][r] * si);
                }
            }
        }

    // ---- coalesced packed store: 4 slabs of 49 x 16B contiguous ----
    if (lane < NTOK) {
        #pragma unroll
        for (int kg = 0; kg < 4; ++kg) {
            uint4 v = *(const uint4*)(Os + kg * (NTOK * 8) + lane * 8);
            *(uint4*)(o1b + ((size_t)(h * 4 + kg) * Mc + (size_t)b * NTOK + lane) * 8) = v;
        }
    }
}

// ---------------- launch ------------------------------------------------------
extern "C" void kernel_launch(void* const* d_in, const int* in_sizes, int n_in,
                              void* d_out, int out_size, void* d_ws, size_t ws_size,
                              hipStream_t stream)
{
    const float* x          = (const float*)d_in[0];
    const float* mask       = (const float*)d_in[1];
    const float* qkv_w      = (const float*)d_in[2];
    const float* qkv_b      = (const float*)d_in[3];
    const float* proj_w     = (const float*)d_in[4];
    const float* proj_b     = (const float*)d_in[5];
    const float* bias_table = (const float*)d_in[6];
    const int*   rel_index  = (const int*)d_in[7];
    float* outp = (float*)d_out;

    const int B_TOTAL = 2048;
    char* ws = (char*)d_ws;
    size_t off = 0;
    auto carve = [&](size_t bytes) -> void* {
        void* p = ws + off; off += (bytes + 255) & ~(size_t)255; return p;
    };
    unsigned short* WpQ = (unsigned short*)carve((size_t)256 * 768 * 2);
    unsigned short* WpP = (unsigned short*)carve((size_t)256 * 256 * 2);
    float* bm = (float*)carve((size_t)64 * NHEAD * NTOK * NTOK * 4);
    const size_t fixed = off;
    const size_t PER_WIN = (size_t)NTOK * 768 * 2 + (size_t)NTOK * 256 * 2;
    size_t avail = (ws_size > fixed + 1024) ? (ws_size - fixed - 1024) : 0;
    int chunkW = (int)(avail / PER_WIN);
    if (chunkW > B_TOTAL) chunkW = B_TOTAL;
    chunkW &= ~127;
    if (chunkW < 128) chunkW = 128;
    unsigned short* qkvb = (unsigned short*)carve((size_t)chunkW * NTOK * 768 * 2);
    unsigned short* o1b  = (unsigned short*)carve((size_t)chunkW * NTOK * 256 * 2);

    pack_w<<<(256 * 768 + 255) / 256, 256, 0, stream>>>(qkv_w, WpQ, 256, 768);
    pack_w<<<(256 * 256 + 255) / 256, 256, 0, stream>>>(proj_w, WpP, 256, 256);
    bm_build<<<(64 * NHEAD * NTOK * NTOK + 255) / 256, 256, 0, stream>>>(
        bias_table, rel_index, mask, bm);

    for (int w0 = 0; w0 < B_TOTAL; w0 += chunkW) {
        int wc = B_TOTAL - w0; if (wc > chunkW) wc = chunkW;
        const int Mc = wc * NTOK;
        const int nbm = Mc / 128;
        gemm_mfma<true, true ><<<dim3(nbm * 6), 256, 0, stream>>>(
            x + (size_t)w0 * NTOK * DIMC, WpQ, qkv_b, qkvb, 768, Mc, nbm);
        attn_mfma<<<dim3(NHEAD / 2, wc), 128, 0, stream>>>(qkvb, bm, o1b, w0, Mc);
        gemm_mfma<false, false><<<dim3(nbm * 2), 256, 0, stream>>>(
            o1b, WpP, proj_b, outp + (size_t)w0 * NTOK * DIMC, 256, Mc, nbm);
    }
}

// Round 6
// 389.385 us; speedup vs baseline: 1.2101x; 1.2101x over previous
//
#include <hip/hip_runtime.h>

#define NTOK 49
#define NHEAD 8
#define HDIM 32
#define DIMC 256
#define SCALE_F 0.17677669529663687f

typedef __attribute__((ext_vector_type(8))) short short8;
typedef __attribute__((ext_vector_type(4))) float f32x4;

#define AS1P(p) ((__attribute__((address_space(1))) void*)(p))
#define AS3P(p) ((__attribute__((address_space(3))) void*)(p))

__device__ inline unsigned short f2bf(float f) {
    unsigned int u = __float_as_uint(f);
    u += 0x7fffu + ((u >> 16) & 1u);
    return (unsigned short)(u >> 16);
}

// ---------------- fp32 -> bf16 + k-major pack via LDS transpose -------------
// in:  x[M][256] fp32 (row-major, streamed 64-row tiles = 64KB contiguous)
// out: xp[32][M][8] bf16 (each wave stores 1KB contiguous per slab)
// LDS tile T[kc][64 r][8] with XOR swizzle (r ^ (kc&7)) -> conflict-free
// b128 writes (phase 1) and reads (phase 2).
__global__ __launch_bounds__(256) void conv_pack(const float* __restrict__ in,
    unsigned short* __restrict__ xp, int M)
{
    __shared__ __align__(16) unsigned short T[32 * 64 * 8];  // 32 KB
    const int t = threadIdx.x;
    const size_t m0 = (size_t)blockIdx.x * 64;
    const float* src = in + m0 * 256;
    #pragma unroll
    for (int i = 0; i < 8; ++i) {
        const int li = i * 256 + t;      // 8-float chunk index 0..2047
        const int r  = li >> 5;          // row 0..63
        const int kc = li & 31;          // k-chunk 0..31
        float4 a = ((const float4*)src)[li * 2];
        float4 b = ((const float4*)src)[li * 2 + 1];
        union { unsigned short s[8]; uint4 v; } u;
        u.s[0] = f2bf(a.x); u.s[1] = f2bf(a.y); u.s[2] = f2bf(a.z); u.s[3] = f2bf(a.w);
        u.s[4] = f2bf(b.x); u.s[5] = f2bf(b.y); u.s[6] = f2bf(b.z); u.s[7] = f2bf(b.w);
        *(uint4*)(T + kc * 512 + ((r ^ (kc & 7)) * 8)) = u.v;
    }
    __syncthreads();
    #pragma unroll
    for (int j = 0; j < 8; ++j) {
        const int li = j * 256 + t;      // 16B-chunk index 0..2047
        const int kc = li >> 6;          // 0..31 (uniform per wave)
        const int r  = li & 63;          // = lane
        uint4 v = *(const uint4*)(T + kc * 512 + ((r ^ (kc & 7)) * 8));
        *(uint4*)(xp + ((size_t)kc * M + m0 + r) * 8) = v;
    }
}

// ---------------- pack W[K,N] fp32 -> Wp[K/8][N][8] bf16 --------------------
__global__ __launch_bounds__(256) void pack_w(const float* __restrict__ W,
    unsigned short* __restrict__ Wp, int K, int N)
{
    int idx = blockIdx.x * 256 + threadIdx.x;
    if (idx >= K * N) return;
    int k = idx / N, n = idx - k * N;
    Wp[((size_t)(k >> 3) * N + n) * 8 + (k & 7)] = f2bf(W[idx]);
}

// ---------------- bias+mask combined table bm[w][h][i][j] -------------------
__global__ __launch_bounds__(256) void bm_build(const float* __restrict__ bias_table,
    const int* __restrict__ rel_index, const float* __restrict__ mask,
    float* __restrict__ bm)
{
    int idx = blockIdx.x * 256 + threadIdx.x;
    if (idx >= 64 * NHEAD * NTOK * NTOK) return;
    int wh = idx / (NTOK * NTOK);
    int ij = idx - wh * (NTOK * NTOK);
    int w = wh >> 3, h = wh & 7;
    bm[idx] = bias_table[rel_index[ij] * NHEAD + h] + mask[(size_t)w * (NTOK * NTOK) + ij];
}

// ---------------- bf16 MFMA GEMM: Y[M,N] = A[M,256] @ W[256,N] + Bv ---------
// EXACT R1 structure (measured 83 us on QKV): 128x128 tile, 4 waves, BK=32,
// A and B k-major packed [32][rows][8], 4x global_load_lds, 2 barriers/step.
// Swapped-operand MFMA (C^T fragments) -> vectorized epilogue.
// 1-D grid with XCD-bijective swizzle when nbm % 8 == 0.
template <bool OUT_BF16>
__global__ __launch_bounds__(256) void gemm_mfma(
    const unsigned short* __restrict__ Ap,   // [32][M][8] bf16 packed
    const unsigned short* __restrict__ Wp,   // [32][N][8] bf16 packed
    const float* __restrict__ Bv,            // [N]
    void* __restrict__ Yv,                   // [M][N]
    int N, int M, int nbm)
{
    __shared__ __align__(16) unsigned short As[4096];  // [4 kg][128 m][8 ki]
    __shared__ __align__(16) unsigned short Bs[4096];  // [4 kg][128 n][8 ki]

    const int tid  = threadIdx.x;
    const int lane = tid & 63;
    const int wv   = tid >> 6;
    const int quad = lane >> 4;
    const int l15  = lane & 15;

    const int nbn = N >> 7;
    const int lin = blockIdx.x;
    int mblk, nblk;
    if ((nbm & 7) == 0) {
        const int xcd = lin & 7;
        const int g   = lin >> 3;
        const int gm  = g / nbn;
        mblk = xcd * (nbm >> 3) + gm;
        nblk = g - gm * nbn;
    } else {
        mblk = lin / nbn;
        nblk = lin - mblk * nbn;
    }
    const long m0 = (long)mblk * 128;
    const int  n0 = nblk * 128;
    const int  wm = (wv >> 1) * 64;
    const int  wn = (wv & 1) * 64;

    const unsigned short* ga0 = Ap + ((size_t)wv * M + m0 + lane) * 8;
    const unsigned short* ga1 = ga0 + 64 * 8;
    const unsigned short* gb0 = Wp + ((size_t)wv * N + n0 + lane) * 8;
    const unsigned short* gb1 = gb0 + 64 * 8;

    f32x4 acc[4][4];
    #pragma unroll
    for (int i = 0; i < 4; ++i)
        #pragma unroll
        for (int j = 0; j < 4; ++j) acc[i][j] = (f32x4){0.f, 0.f, 0.f, 0.f};

    for (int k0 = 0; k0 < 256; k0 += 32) {
        const size_t aofs = (size_t)(k0 >> 3) * M * 8;
        const size_t bofs = (size_t)(k0 >> 3) * N * 8;
        __builtin_amdgcn_global_load_lds(AS1P(ga0 + aofs), AS3P(As + wv * 1024),       16, 0, 0);
        __builtin_amdgcn_global_load_lds(AS1P(ga1 + aofs), AS3P(As + wv * 1024 + 512), 16, 0, 0);
        __builtin_amdgcn_global_load_lds(AS1P(gb0 + bofs), AS3P(Bs + wv * 1024),       16, 0, 0);
        __builtin_amdgcn_global_load_lds(AS1P(gb1 + bofs), AS3P(Bs + wv * 1024 + 512), 16, 0, 0);
        __syncthreads();
        short8 af[4], bq[4];
        #pragma unroll
        for (int t = 0; t < 4; ++t) {
            af[t] = *(const short8*)(As + quad * 1024 + (wm + t * 16 + l15) * 8);
            bq[t] = *(const short8*)(Bs + quad * 1024 + (wn + t * 16 + l15) * 8);
        }
        // swapped operands: acc[ti][tj] holds C^T fragment:
        //   C row  = wm + ti*16 + l15             (lane-resident)
        //   C cols = wn + tj*16 + quad*4 + (0..3) (register-resident, consecutive)
        #pragma unroll
        for (int ti = 0; ti < 4; ++ti)
            #pragma unroll
            for (int tj = 0; tj < 4; ++tj)
                acc[ti][tj] = __builtin_amdgcn_mfma_f32_16x16x32_bf16(bq[tj], af[ti], acc[ti][tj], 0, 0, 0);
        __syncthreads();
    }

    float4 bv4[4];
    #pragma unroll
    for (int tj = 0; tj < 4; ++tj)
        bv4[tj] = *(const float4*)(Bv + n0 + wn + tj * 16 + quad * 4);

    #pragma unroll
    for (int ti = 0; ti < 4; ++ti) {
        const long row = m0 + wm + ti * 16 + l15;
        #pragma unroll
        for (int tj = 0; tj < 4; ++tj) {
            const int col = n0 + wn + tj * 16 + quad * 4;
            const float v0 = acc[ti][tj][0] + bv4[tj].x;
            const float v1 = acc[ti][tj][1] + bv4[tj].y;
            const float v2 = acc[ti][tj][2] + bv4[tj].z;
            const float v3 = acc[ti][tj][3] + bv4[tj].w;
            if (OUT_BF16) {
                uint2 u;
                u.x = (unsigned int)f2bf(v0) | ((unsigned int)f2bf(v1) << 16);
                u.y = (unsigned int)f2bf(v2) | ((unsigned int)f2bf(v3) << 16);
                *(uint2*)((unsigned short*)Yv + row * N + col) = u;
            } else {
                float4 o = {v0, v1, v2, v3};
                *(float4*)((float*)Yv + row * N + col) = o;
            }
        }
    }
}

// ---------------- MFMA attention: 2 waves/block, direct Q/K frag loads ------
// qkvb: [wc*49][768] bf16, col = s*256 + h*32 + d.
// o1b: k-major packed [32][Mc][8] bf16 (feeds proj GEMM's A path), written
// via LDS slab restage -> 49x16B contiguous stores per k-group.
// Softmax WITHOUT max-subtraction (scores bounded; expf(-inf)=0 pads col>=49).
__global__ __launch_bounds__(128) void attn_mfma(
    const unsigned short* __restrict__ qkvb,
    const float* __restrict__ bm,        // [64][8][49][49]
    unsigned short* __restrict__ o1b,
    int win0, int Mc)
{
    __shared__ __align__(16) unsigned short SMEM[2 * 3528];

    const int wvid = threadIdx.x >> 6;
    const int lane = threadIdx.x & 63;
    const int h    = blockIdx.x * 2 + wvid;     // head
    const int b    = blockIdx.y;                // local window
    const int w    = (win0 + b) & 63;
    const int quad = lane >> 4;
    const int l15  = lane & 15;

    unsigned short* Vt = SMEM + wvid * 3528;   // [32 d][72], phase 1
    unsigned short* Ps = SMEM + wvid * 3528;   // [49 row][72], phase 2
    unsigned short* Os = SMEM + wvid * 3528;   // [4 kg][49][8], phase 3

    const unsigned short* wbase = qkvb + (size_t)b * NTOK * 768 + h * HDIM;

    // ---- stage V^T: lane = token (clamped), 32 scalar b16 writes ----
    {
        const int tok = (lane < NTOK) ? lane : (NTOK - 1);
        const unsigned short* vp = wbase + (size_t)tok * 768 + 512;
        #pragma unroll
        for (int c = 0; c < 4; ++c) {
            uint4 vv = *(const uint4*)(vp + c * 8);
            unsigned int uu[4] = {vv.x, vv.y, vv.z, vv.w};
            #pragma unroll
            for (int e = 0; e < 4; ++e) {
                int d = c * 8 + e * 2;
                Vt[d * 72 + lane]       = (unsigned short)(uu[e] & 0xffffu);
                Vt[(d + 1) * 72 + lane] = (unsigned short)(uu[e] >> 16);
            }
        }
    }

    // ---- Q/K fragments direct from global (16B contiguous per lane) ----
    short8 aq[4], bk[4];
    #pragma unroll
    for (int t = 0; t < 4; ++t) {
        int row = t * 16 + l15; if (row >= NTOK) row = NTOK - 1;
        const unsigned short* rp = wbase + (size_t)row * 768 + quad * 8;
        aq[t] = *(const short8*)(rp);
        bk[t] = *(const short8*)(rp + 256);
    }

    // ---- S = Q K^T (16 mfma, K=32) ----
    f32x4 sa[4][4];
    #pragma unroll
    for (int ti = 0; ti < 4; ++ti)
        #pragma unroll
        for (int tj = 0; tj < 4; ++tj) {
            f32x4 z = (f32x4){0.f, 0.f, 0.f, 0.f};
            sa[ti][tj] = __builtin_amdgcn_mfma_f32_16x16x32_bf16(aq[ti], bk[tj], z, 0, 0, 0);
        }

    // ---- read V fragments BEFORE P overwrites the aliased LDS ----
    short8 vb2[2][2];
    #pragma unroll
    for (int td = 0; td < 2; ++td)
        #pragma unroll
        for (int kc = 0; kc < 2; ++kc)
            vb2[td][kc] = *(const short8*)(Vt + (td * 16 + l15) * 72 + kc * 32 + quad * 8);

    // ---- scale + bias + mask, softmax (no max-sub) across row ----
    const float* bmb = bm + (size_t)(w * NHEAD + h) * (NTOK * NTOK);
    float inv[4][4];
    #pragma unroll
    for (int ti = 0; ti < 4; ++ti) {
        #pragma unroll
        for (int r = 0; r < 4; ++r) {
            const int row = ti * 16 + quad * 4 + r;
            float sv[4];
            #pragma unroll
            for (int tj = 0; tj < 4; ++tj) {
                const int col = tj * 16 + l15;
                float s;
                if (col < NTOK) {
                    float add = (row < NTOK) ? bmb[row * NTOK + col] : 0.f;
                    s = sa[ti][tj][r] * SCALE_F + add;
                } else {
                    s = -__builtin_inff();
                }
                sv[tj] = s;
            }
            float e0 = __expf(sv[0]), e1 = __expf(sv[1]);
            float e2 = __expf(sv[2]), e3 = __expf(sv[3]);
            sa[ti][0][r] = e0; sa[ti][1][r] = e1; sa[ti][2][r] = e2; sa[ti][3][r] = e3;
            float sum = (e0 + e1) + (e2 + e3);
            sum += __shfl_xor(sum, 1, 16);
            sum += __shfl_xor(sum, 2, 16);
            sum += __shfl_xor(sum, 4, 16);
            sum += __shfl_xor(sum, 8, 16);
            inv[ti][r] = 1.f / sum;
        }
    }

    // ---- make sure both waves' V-fragment reads retired before P overwrite ----
    __syncthreads();

    // ---- P (unnormalized e, bf16) -> LDS row-major [49][72] ----
    #pragma unroll
    for (int ti = 0; ti < 4; ++ti)
        #pragma unroll
        for (int r = 0; r < 4; ++r) {
            const int row = ti * 16 + quad * 4 + r;
            if (row < NTOK) {
                #pragma unroll
                for (int tj = 0; tj < 4; ++tj)
                    Ps[row * 72 + tj * 16 + l15] = f2bf(sa[ti][tj][r]);
            }
        }

    // ---- O = P V (K=64 via 2 chunks), rows clamped (rows>=49 unused) ----
    short8 pa[4][2];
    #pragma unroll
    for (int ti = 0; ti < 4; ++ti) {
        int row = ti * 16 + l15; if (row >= NTOK) row = NTOK - 1;
        #pragma unroll
        for (int kc = 0; kc < 2; ++kc)
            pa[ti][kc] = *(const short8*)(Ps + row * 72 + kc * 32 + quad * 8);
    }
    f32x4 oa[4][2];
    #pragma unroll
    for (int ti = 0; ti < 4; ++ti)
        #pragma unroll
        for (int td = 0; td < 2; ++td) {
            f32x4 z = (f32x4){0.f, 0.f, 0.f, 0.f};
            z = __builtin_amdgcn_mfma_f32_16x16x32_bf16(pa[ti][0], vb2[td][0], z, 0, 0, 0);
            oa[ti][td] = __builtin_amdgcn_mfma_f32_16x16x32_bf16(pa[ti][1], vb2[td][1], z, 0, 0, 0);
        }

    // ---- normalize + restage O into wave-private slab LDS [4 kg][49][8] ----
    #pragma unroll
    for (int ti = 0; ti < 4; ++ti)
        #pragma unroll
        for (int r = 0; r < 4; ++r) {
            const int row = ti * 16 + quad * 4 + r;
            if (row < NTOK) {
                const float si = inv[ti][r];
                #pragma unroll
                for (int td = 0; td < 2; ++td) {
                    const int d = td * 16 + l15;    // 0..31 within head
                    Os[(d >> 3) * (NTOK * 8) + row * 8 + (d & 7)] =
                        f2bf(oa[ti][td][r] * si);
                }
            }
        }

    // ---- coalesced packed store: 4 slabs of 49 x 16B contiguous ----
    if (lane < NTOK) {
        #pragma unroll
        for (int kg = 0; kg < 4; ++kg) {
            uint4 v = *(const uint4*)(Os + kg * (NTOK * 8) + lane * 8);
            *(uint4*)(o1b + ((size_t)(h * 4 + kg) * Mc + (size_t)b * NTOK + lane) * 8) = v;
        }
    }
}

// ---------------- launch ------------------------------------------------------
extern "C" void kernel_launch(void* const* d_in, const int* in_sizes, int n_in,
                              void* d_out, int out_size, void* d_ws, size_t ws_size,
                              hipStream_t stream)
{
    const float* x          = (const float*)d_in[0];
    const float* mask       = (const float*)d_in[1];
    const float* qkv_w      = (const float*)d_in[2];
    const float* qkv_b      = (const float*)d_in[3];
    const float* proj_w     = (const float*)d_in[4];
    const float* proj_b     = (const float*)d_in[5];
    const float* bias_table = (const float*)d_in[6];
    const int*   rel_index  = (const int*)d_in[7];
    float* outp = (float*)d_out;

    const int B_TOTAL = 2048;
    char* ws = (char*)d_ws;
    size_t off = 0;
    auto carve = [&](size_t bytes) -> void* {
        void* p = ws + off; off += (bytes + 255) & ~(size_t)255; return p;
    };
    unsigned short* WpQ = (unsigned short*)carve((size_t)256 * 768 * 2);
    unsigned short* WpP = (unsigned short*)carve((size_t)256 * 256 * 2);
    float* bm = (float*)carve((size_t)64 * NHEAD * NTOK * NTOK * 4);
    const size_t fixed = off;
    const size_t PER_WIN = (size_t)NTOK * 256 * 2 + (size_t)NTOK * 768 * 2 + (size_t)NTOK * 256 * 2;
    size_t avail = (ws_size > fixed + 1024) ? (ws_size - fixed - 1024) : 0;
    int chunkW = (int)(avail / PER_WIN);
    if (chunkW > B_TOTAL) chunkW = B_TOTAL;
    chunkW &= ~127;
    if (chunkW < 128) chunkW = 128;
    unsigned short* x_bf = (unsigned short*)carve((size_t)chunkW * NTOK * 256 * 2);
    unsigned short* qkvb = (unsigned short*)carve((size_t)chunkW * NTOK * 768 * 2);
    unsigned short* o1b  = (unsigned short*)carve((size_t)chunkW * NTOK * 256 * 2);

    pack_w<<<(256 * 768 + 255) / 256, 256, 0, stream>>>(qkv_w, WpQ, 256, 768);
    pack_w<<<(256 * 256 + 255) / 256, 256, 0, stream>>>(proj_w, WpP, 256, 256);
    bm_build<<<(64 * NHEAD * NTOK * NTOK + 255) / 256, 256, 0, stream>>>(
        bias_table, rel_index, mask, bm);

    for (int w0 = 0; w0 < B_TOTAL; w0 += chunkW) {
        int wc = B_TOTAL - w0; if (wc > chunkW) wc = chunkW;
        const int Mc = wc * NTOK;
        const int nbm = Mc / 128;
        conv_pack<<<Mc / 64, 256, 0, stream>>>(
            x + (size_t)w0 * NTOK * DIMC, x_bf, Mc);
        gemm_mfma<true ><<<dim3(nbm * 6), 256, 0, stream>>>(x_bf, WpQ, qkv_b, qkvb, 768, Mc, nbm);
        attn_mfma<<<dim3(NHEAD / 2, wc), 128, 0, stream>>>(qkvb, bm, o1b, w0, Mc);
        gemm_mfma<false><<<dim3(nbm * 2), 256, 0, stream>>>(
            o1b, WpP, proj_b, outp + (size_t)w0 * NTOK * DIMC, 256, Mc, nbm);
    }
}